// Round 1
// baseline (753.378 us; speedup 1.0000x reference)
//
#include <hip/hip_runtime.h>
#include <math.h>

#define EPS 1e-5f

typedef __attribute__((ext_vector_type(4))) float floatx4;
typedef __attribute__((ext_vector_type(8))) short shortx8;

__device__ __forceinline__ unsigned short f2bf(float f){
  union { float f; unsigned u; } v; v.f = f;
  unsigned r = v.u + 0x7FFFu + ((v.u >> 16) & 1u);
  return (unsigned short)(r >> 16);
}
__device__ __forceinline__ float bf2f(unsigned short s){
  union { unsigned u; float f; } v; v.u = ((unsigned)s) << 16;
  return v.f;
}

// ---------------- K0: We^T -> bf16 ----------------
__global__ __launch_bounds__(256) void k_prep(const float* __restrict__ We,
                                              unsigned short* __restrict__ WeT){
  int n = blockIdx.x, k = threadIdx.x;
  WeT[n*256 + k] = f2bf(We[k*256 + n]);
}

// ---------------- K1: S = h@Ws+bs+be, T = h@Wd+bd ----------------
__global__ __launch_bounds__(256) void k_st(
    const float* __restrict__ h, const float* __restrict__ Ws, const float* __restrict__ bs,
    const float* __restrict__ be, const float* __restrict__ Wd, const float* __restrict__ bd,
    float* __restrict__ S, float* __restrict__ T)
{
  __shared__ float x[4][256];
  int t = threadIdx.x;
  int row0 = blockIdx.x*4;
  int which = blockIdx.y;
#pragma unroll
  for (int r=0;r<4;r++) x[r][t] = h[(row0+r)*256 + t];
  __syncthreads();
  const float* W = which ? Wd : Ws;
  float bv = which ? bd[t] : (bs[t] + be[t]);
  float acc[4] = {bv,bv,bv,bv};
  for (int k=0;k<256;k++){
    float wv = W[k*256 + t];
#pragma unroll
    for (int r=0;r<4;r++) acc[r] += x[r][k]*wv;
  }
  float* outp = which ? T : S;
#pragma unroll
  for (int r=0;r<4;r++) outp[(row0+r)*256 + t] = acc[r];
}

// ---------------- K2: e_new + fused bias ----------------
// block: 256 thr (4 waves), tile = 64 rows(j) x 256 cols(d), one (b,i) per block.
__global__ __launch_bounds__(256) void k_edge(
    const float* __restrict__ e, const unsigned short* __restrict__ WeT,
    const float* __restrict__ S, const float* __restrict__ T,
    const float* __restrict__ Wb, const float* __restrict__ bbv,
    float* __restrict__ eo, float* __restrict__ bias)
{
  __shared__ __align__(16) unsigned short smem[16896]; // As(64x40) + Bs(256x40) | En(64x264)
  __shared__ float sbuf[256];
  __shared__ __align__(16) unsigned short WbT[16*256];
  unsigned short* As = smem;
  unsigned short* Bs = smem + 2560;
  unsigned short* En = smem;

  const int tid = threadIdx.x;
  const int blk = blockIdx.x;
  const int jt = blk & 3;
  const int i  = (blk >> 2) & 255;
  const int b  = blk >> 10;
  const int j0 = jt * 64;
  const int w = tid >> 6, l = tid & 63;
  const int lrow = l & 15, quad = l >> 4;

  sbuf[tid] = S[((b << 8) + i) * 256 + tid];
  {
    const float* wbp = Wb + tid * 8;
    float4 w0 = *(const float4*)wbp;
    float4 w1 = *(const float4*)(wbp + 4);
    WbT[0*256 + tid] = f2bf(w0.x);
    WbT[1*256 + tid] = f2bf(w0.y);
    WbT[2*256 + tid] = f2bf(w0.z);
    WbT[3*256 + tid] = f2bf(w0.w);
    WbT[4*256 + tid] = f2bf(w1.x);
    WbT[5*256 + tid] = f2bf(w1.y);
    WbT[6*256 + tid] = f2bf(w1.z);
    WbT[7*256 + tid] = f2bf(w1.w);
#pragma unroll
    for (int hh = 8; hh < 16; hh++) WbT[hh*256 + tid] = 0; // cols 8..15 discarded anyway
  }

  floatx4 acc[16];
#pragma unroll
  for (int t = 0; t < 16; t++) acc[t] = (floatx4){0.f,0.f,0.f,0.f};

  const float* eBase = e + ((size_t)((b*256 + i)*256 + j0)) * 256;

  for (int c = 0; c < 8; c++){
    const int k0 = c * 32;
    __syncthreads();
    // stage A: 64 rows x 32 k (fp32 -> bf16)
#pragma unroll
    for (int s = 0; s < 2; s++){
      int f = tid + s*256;
      int r = f >> 3, q = f & 7;
      float4 v = *(const float4*)(eBase + r*256 + k0 + q*4);
      unsigned short* dst = As + r*40 + q*4;
      dst[0]=f2bf(v.x); dst[1]=f2bf(v.y); dst[2]=f2bf(v.z); dst[3]=f2bf(v.w);
    }
    // stage B^T: WeT rows n, k0..k0+31 (already bf16)
#pragma unroll
    for (int s = 0; s < 4; s++){
      int f = tid + s*256;
      int n = f >> 2, seg = f & 3;
      uint4 v = *(const uint4*)(WeT + n*256 + k0 + seg*8);
      *(uint4*)(Bs + n*40 + seg*8) = v;
    }
    __syncthreads();
    shortx8 af = *(const shortx8*)(As + (w*16 + lrow)*40 + quad*8);
#pragma unroll
    for (int t = 0; t < 16; t++){
      shortx8 bfrag = *(const shortx8*)(Bs + (t*16 + lrow)*40 + quad*8);
      acc[t] = __builtin_amdgcn_mfma_f32_16x16x32_bf16(af, bfrag, acc[t], 0, 0, 0);
    }
  }
  __syncthreads();
  // epilogue: + S[b,i,d] + T[b,j,d], relu -> En (bf16)
  const float* Tb = T + (size_t)(b*256 + j0) * 256;
#pragma unroll
  for (int reg = 0; reg < 4; reg++){
    int rloc = w*16 + quad*4 + reg;
    const float* Trow = Tb + rloc*256;
#pragma unroll
    for (int t = 0; t < 16; t++){
      int col = t*16 + lrow;
      float v = acc[t][reg] + sbuf[col] + Trow[col];
      v = fmaxf(v, 0.f);
      En[rloc*264 + col] = f2bf(v);
    }
  }
  __syncthreads();
  // coalesced fp32 store of e_new
  float* eop = eo + ((size_t)((b*256 + i)*256 + j0)) * 256;
#pragma unroll
  for (int s = 0; s < 16; s++){
    int fi = tid + s*256;
    int r = fi >> 6, c4 = fi & 63;
    const unsigned short* src = En + r*264 + c4*4;
    float4 v = { bf2f(src[0]), bf2f(src[1]), bf2f(src[2]), bf2f(src[3]) };
    *(float4*)(eop + r*256 + c4*4) = v;
  }
  // fused bias: (64xj, 256xd) @ WbT -> [h=8][j]
  floatx4 accb = (floatx4){0.f,0.f,0.f,0.f};
#pragma unroll
  for (int c = 0; c < 8; c++){
    int k0 = c*32;
    shortx8 af = *(const shortx8*)(En + (w*16 + lrow)*264 + k0 + quad*8);
    shortx8 bfrag = *(const shortx8*)(WbT + lrow*256 + k0 + quad*8);
    accb = __builtin_amdgcn_mfma_f32_16x16x32_bf16(af, bfrag, accb, 0, 0, 0);
  }
  if (lrow < 8){
    float bv = bbv[lrow];
    float* bp = bias + ((size_t)((b*8 + lrow)*256 + i)) * 256;
    int jb = j0 + w*16 + quad*4;
#pragma unroll
    for (int r = 0; r < 4; r++) bp[jb + r] = accb[r] + bv;
  }
}

// ---------------- K3: LN1 + QKV ----------------
__global__ __launch_bounds__(256) void k_ln1_qkv(
    const float* __restrict__ h, const float* __restrict__ g1, const float* __restrict__ b1l,
    const float* __restrict__ Wq, const float* __restrict__ bq,
    float* __restrict__ Q, float* __restrict__ K, float* __restrict__ V)
{
  __shared__ float x[4][256];
  __shared__ float red[256];
  __shared__ float mred[4], vred[4];
  int t = threadIdx.x;
  int row0 = blockIdx.x*4;
  int b = row0 >> 8, i0 = row0 & 255;
#pragma unroll
  for (int r=0;r<4;r++) x[r][t] = h[(row0+r)*256 + t];
  __syncthreads();
  int rr = t>>6, seg = t&63;
  const float* xr = x[rr];
  red[t] = xr[seg*4]+xr[seg*4+1]+xr[seg*4+2]+xr[seg*4+3];
  __syncthreads();
  for (int s=32;s>0;s>>=1){ if(seg<s) red[t]+=red[t+s]; __syncthreads(); }
  if (t<4) mred[t] = red[t*64]*(1.f/256.f);
  __syncthreads();
  float m_r = mred[rr];
  float d0=xr[seg*4]-m_r, d1=xr[seg*4+1]-m_r, d2=xr[seg*4+2]-m_r, d3=xr[seg*4+3]-m_r;
  red[t]=d0*d0+d1*d1+d2*d2+d3*d3;
  __syncthreads();
  for (int s=32;s>0;s>>=1){ if(seg<s) red[t]+=red[t+s]; __syncthreads(); }
  if (t<4) vred[t] = rsqrtf(red[t*64]*(1.f/256.f) + EPS);
  __syncthreads();
  float xn[4];
#pragma unroll
  for (int r=0;r<4;r++) xn[r] = (x[r][t]-mred[r])*vred[r]*g1[t] + b1l[t];
  __syncthreads();
#pragma unroll
  for (int r=0;r<4;r++) x[r][t] = xn[r];
  __syncthreads();
  float a0[4], a1[4], a2[4];
#pragma unroll
  for (int r=0;r<4;r++){ a0[r]=bq[t]; a1[r]=bq[t+256]; a2[r]=bq[t+512]; }
  for (int k=0;k<256;k++){
    float x0=x[0][k], x1=x[1][k], x2=x[2][k], x3=x[3][k];
    float w0=Wq[k*768+t], w1=Wq[k*768+t+256], w2=Wq[k*768+t+512];
    a0[0]+=x0*w0; a0[1]+=x1*w0; a0[2]+=x2*w0; a0[3]+=x3*w0;
    a1[0]+=x0*w1; a1[1]+=x1*w1; a1[2]+=x2*w1; a1[3]+=x3*w1;
    a2[0]+=x0*w2; a2[1]+=x1*w2; a2[2]+=x2*w2; a2[3]+=x3*w2;
  }
  int hd = t&31, hed = t>>5;
#pragma unroll
  for (int r=0;r<4;r++){
    int idx = ((b*8 + hed)*256 + (i0+r))*32 + hd;
    Q[idx] = a0[r]; K[idx] = a1[r]; V[idx] = a2[r];
  }
}

// ---------------- K4: attention, one block per (b,h,i) ----------------
__global__ __launch_bounds__(256) void k_attn(
    const float* __restrict__ Q, const float* __restrict__ K, const float* __restrict__ V,
    const float* __restrict__ bias, float* __restrict__ O)
{
  __shared__ float ksl[256*33];
  __shared__ float q[32];
  __shared__ float sc[256];
  __shared__ float red[256];
  __shared__ float part[8*33];
  int t = threadIdx.x;
  int i = blockIdx.x & 255, bh = blockIdx.x >> 8;
  const float* Kb = K + bh*8192;
  const float* Vb = V + bh*8192;
  if (t < 32) q[t] = Q[(bh*256 + i)*32 + t];
#pragma unroll
  for (int s=0;s<8;s++){
    int f = t + s*256;
    int row = f >> 3, seg = f & 7;
    float4 v = ((const float4*)Kb)[f];
    int base = row*33 + seg*4;
    ksl[base]=v.x; ksl[base+1]=v.y; ksl[base+2]=v.z; ksl[base+3]=v.w;
  }
  __syncthreads();
  float a = 0.f;
  const float* kr = ksl + t*33;
#pragma unroll
  for (int d=0; d<32; d++) a += q[d]*kr[d];
  float sv = a*0.17677669529663687f + bias[((size_t)(bh*256 + i))*256 + t];
  red[t] = sv;
  __syncthreads();
  for (int s=128;s>0;s>>=1){ if (t<s) red[t] = fmaxf(red[t], red[t+s]); __syncthreads(); }
  float mx = red[0];
  __syncthreads();
  float p = expf(sv - mx);
  sc[t] = p; red[t] = p;
  __syncthreads();
  for (int s=128;s>0;s>>=1){ if (t<s) red[t] += red[t+s]; __syncthreads(); }
  float inv = 1.f/red[0];
  int hd = t & 31, grp = t >> 5;
  float oa = 0.f;
  const float* vb2 = Vb + grp*32*32;
#pragma unroll
  for (int jj=0;jj<32;jj++) oa += sc[grp*32+jj] * vb2[jj*32 + hd];
  part[grp*33 + hd] = oa;
  __syncthreads();
  if (t < 32){
    float o = 0.f;
#pragma unroll
    for (int gg=0; gg<8; gg++) o += part[gg*33 + t];
    int b = bh >> 3, hh = bh & 7;
    O[((b*256 + i)*256) + hh*32 + t] = o * inv;
  }
}

// ---------------- K5: h1 = h + O@Wo+bo; y = ln2(h1) ----------------
__global__ __launch_bounds__(256) void k_oproj_ln2(
    const float* __restrict__ O, const float* __restrict__ Wo, const float* __restrict__ bo,
    const float* __restrict__ h, const float* __restrict__ g2, const float* __restrict__ b2l,
    float* __restrict__ h1, float* __restrict__ y)
{
  __shared__ float x[4][256];
  __shared__ float hh[4][256];
  __shared__ float red[256];
  __shared__ float mred[4], vred[4];
  int t = threadIdx.x;
  int row0 = blockIdx.x * 4;
#pragma unroll
  for (int r=0;r<4;r++) x[r][t] = O[(row0+r)*256 + t];
  __syncthreads();
  float acc[4];
#pragma unroll
  for (int r=0;r<4;r++) acc[r] = bo[t];
  for (int k=0;k<256;k++){
    float wv = Wo[k*256 + t];
#pragma unroll
    for (int r=0;r<4;r++) acc[r] += x[r][k]*wv;
  }
#pragma unroll
  for (int r=0;r<4;r++){
    float hv = h[(row0+r)*256 + t] + acc[r];
    hh[r][t] = hv;
    h1[(row0+r)*256 + t] = hv;
  }
  __syncthreads();
  int rr = t>>6, seg = t&63;
  const float* hr = hh[rr];
  red[t] = hr[seg*4]+hr[seg*4+1]+hr[seg*4+2]+hr[seg*4+3];
  __syncthreads();
  for (int s=32;s>0;s>>=1){ if (seg<s) red[t]+=red[t+s]; __syncthreads(); }
  if (t<4) mred[t] = red[t*64]*(1.f/256.f);
  __syncthreads();
  float m_r = mred[rr];
  float d0=hr[seg*4]-m_r, d1=hr[seg*4+1]-m_r, d2=hr[seg*4+2]-m_r, d3=hr[seg*4+3]-m_r;
  red[t] = d0*d0+d1*d1+d2*d2+d3*d3;
  __syncthreads();
  for (int s=32;s>0;s>>=1){ if (seg<s) red[t]+=red[t+s]; __syncthreads(); }
  if (t<4) vred[t] = rsqrtf(red[t*64]*(1.f/256.f) + EPS);
  __syncthreads();
#pragma unroll
  for (int r=0;r<4;r++)
    y[(row0+r)*256 + t] = (hh[r][t]-mred[r])*vred[r]*g2[t] + b2l[t];
}

// ---------------- K6: FFN1 + exact GELU ----------------
__global__ __launch_bounds__(256) void k_ffn1(
    const float* __restrict__ y, const float* __restrict__ W1, const float* __restrict__ b1,
    float* __restrict__ G)
{
  __shared__ float x[4][256];
  int t = threadIdx.x;
  int row0 = blockIdx.x*4;
#pragma unroll
  for (int r=0;r<4;r++) x[r][t] = y[(row0+r)*256 + t];
  __syncthreads();
  float acc[4][4];
#pragma unroll
  for (int c=0;c<4;c++){
    float bv = b1[t + c*256];
#pragma unroll
    for (int r=0;r<4;r++) acc[c][r] = bv;
  }
  for (int k=0;k<256;k++){
    float x0=x[0][k],x1=x[1][k],x2=x[2][k],x3=x[3][k];
#pragma unroll
    for (int c=0;c<4;c++){
      float wv = W1[k*1024 + t + c*256];
      acc[c][0]+=x0*wv; acc[c][1]+=x1*wv; acc[c][2]+=x2*wv; acc[c][3]+=x3*wv;
    }
  }
#pragma unroll
  for (int c=0;c<4;c++){
#pragma unroll
    for (int r=0;r<4;r++){
      float v = acc[c][r];
      float ge = 0.5f*v*(1.f + erff(v*0.70710678118654752f));
      G[(row0+r)*1024 + t + c*256] = ge;
    }
  }
}

// ---------------- K7: FFN2 + residual -> h2 ----------------
__global__ __launch_bounds__(256) void k_ffn2(
    const float* __restrict__ G, const float* __restrict__ W2, const float* __restrict__ b2,
    const float* __restrict__ h1, float* __restrict__ out)
{
  __shared__ float g[4*1024];
  int t = threadIdx.x;
  int row0 = blockIdx.x*4;
  const float4* gl = (const float4*)(G + (size_t)row0*1024);
  float4* gs = (float4*)g;
#pragma unroll
  for (int s=0;s<4;s++) gs[t + s*256] = gl[t + s*256];
  __syncthreads();
  float acc[4];
#pragma unroll
  for (int r=0;r<4;r++) acc[r] = b2[t];
  for (int k=0;k<1024;k++){
    float wv = W2[k*256 + t];
#pragma unroll
    for (int r=0;r<4;r++) acc[r] += g[r*1024 + k]*wv;
  }
#pragma unroll
  for (int r=0;r<4;r++) out[(row0+r)*256 + t] = h1[(row0+r)*256 + t] + acc[r];
}

extern "C" void kernel_launch(void* const* d_in, const int* in_sizes, int n_in,
                              void* d_out, int out_size, void* d_ws, size_t ws_size,
                              hipStream_t stream)
{
  (void)in_sizes; (void)n_in; (void)out_size; (void)ws_size;
  const float* h    = (const float*)d_in[0];
  const float* e    = (const float*)d_in[1];
  const float* We   = (const float*)d_in[2];
  const float* be   = (const float*)d_in[3];
  const float* Ws   = (const float*)d_in[4];
  const float* bs   = (const float*)d_in[5];
  const float* Wd   = (const float*)d_in[6];
  const float* bd   = (const float*)d_in[7];
  const float* Wb   = (const float*)d_in[8];
  const float* bb   = (const float*)d_in[9];
  const float* g1   = (const float*)d_in[10];
  const float* b1l  = (const float*)d_in[11];
  const float* Wqkv = (const float*)d_in[12];
  const float* bqkv = (const float*)d_in[13];
  const float* Wo   = (const float*)d_in[14];
  const float* bo   = (const float*)d_in[15];
  const float* g2   = (const float*)d_in[16];
  const float* b2l  = (const float*)d_in[17];
  const float* W1   = (const float*)d_in[18];
  const float* b1f  = (const float*)d_in[19];
  const float* W2   = (const float*)d_in[20];
  const float* b2f  = (const float*)d_in[21];

  float* out   = (float*)d_out;
  float* h2_o  = out;               // [B,N,D] = 262144
  float* e_o   = out + 262144;      // [B,N,N,D] = 67108864

  float* wsf = (float*)d_ws;
  unsigned short* WeT = (unsigned short*)d_ws;   // 65536 bf16 = 32768 float slots
  float* S_   = wsf + 32768;
  float* T_   = wsf + 294912;
  float* bias = wsf + 557056;    // [B,H,N,N] = 2097152
  float* Q_   = wsf + 2654208;
  float* K_   = wsf + 2916352;
  float* V_   = wsf + 3178496;
  float* O_   = wsf + 3440640;
  float* h1_  = wsf + 3702784;
  float* y_   = wsf + 3964928;
  float* G_   = wsf + 4227072;   // [B,N,DFF] = 1048576 -> end 5275648 floats (~21.1 MB)

  k_prep    <<<dim3(256),    dim3(256), 0, stream>>>(We, WeT);
  k_st      <<<dim3(256, 2), dim3(256), 0, stream>>>(h, Ws, bs, be, Wd, bd, S_, T_);
  k_edge    <<<dim3(4096),   dim3(256), 0, stream>>>(e, WeT, S_, T_, Wb, bb, e_o, bias);
  k_ln1_qkv <<<dim3(256),    dim3(256), 0, stream>>>(h, g1, b1l, Wqkv, bqkv, Q_, K_, V_);
  k_attn    <<<dim3(8192),   dim3(256), 0, stream>>>(Q_, K_, V_, bias, O_);
  k_oproj_ln2<<<dim3(256),   dim3(256), 0, stream>>>(O_, Wo, bo, h, g2, b2l, h1_, y_);
  k_ffn1    <<<dim3(256),    dim3(256), 0, stream>>>(y_, W1, b1f, G_);
  k_ffn2    <<<dim3(256),    dim3(256), 0, stream>>>(G_, W2, b2f, h1_, h2_o);
}

// Round 2
// 667.826 us; speedup vs baseline: 1.1281x; 1.1281x over previous
//
#include <hip/hip_runtime.h>
#include <math.h>

#define EPS 1e-5f

typedef __attribute__((ext_vector_type(4))) float floatx4;
typedef __attribute__((ext_vector_type(8))) short shortx8;

__device__ __forceinline__ unsigned short f2bf(float f){
  union { float f; unsigned u; } v; v.f = f;
  unsigned r = v.u + 0x7FFFu + ((v.u >> 16) & 1u);
  return (unsigned short)(r >> 16);
}
__device__ __forceinline__ float bf2f(unsigned short s){
  union { unsigned u; float f; } v; v.u = ((unsigned)s) << 16;
  return v.f;
}

// ---------------- K0: all weights -> bf16 transposed [n][k] ----------------
__global__ __launch_bounds__(256) void k_prep(
    const float* __restrict__ We, const float* __restrict__ Ws, const float* __restrict__ Wd,
    const float* __restrict__ Wqkv, const float* __restrict__ Wo, const float* __restrict__ W1,
    const float* __restrict__ W2, const float* __restrict__ Wb,
    unsigned short* __restrict__ WeT, unsigned short* __restrict__ WsT,
    unsigned short* __restrict__ WdT, unsigned short* __restrict__ WqkvT,
    unsigned short* __restrict__ WoT, unsigned short* __restrict__ W1T,
    unsigned short* __restrict__ W2T, unsigned short* __restrict__ WbT16)
{
  const int blk = blockIdx.x, tid = threadIdx.x;
  if (blk == 240){
#pragma unroll
    for (int hh=0; hh<8; hh++) WbT16[hh*256+tid] = f2bf(Wb[tid*8+hh]);
#pragma unroll
    for (int hh=8; hh<16; hh++) WbT16[hh*256+tid] = 0;
    return;
  }
  const float* src; unsigned short* dst; int K, N, t;
  if (blk < 16)      { src=We;   dst=WeT;   K=256;  N=256;  t=blk; }
  else if (blk < 32) { src=Ws;   dst=WsT;   K=256;  N=256;  t=blk-16; }
  else if (blk < 48) { src=Wd;   dst=WdT;   K=256;  N=256;  t=blk-32; }
  else if (blk < 96) { src=Wqkv; dst=WqkvT; K=256;  N=768;  t=blk-48; }
  else if (blk < 112){ src=Wo;   dst=WoT;   K=256;  N=256;  t=blk-96; }
  else if (blk < 176){ src=W1;   dst=W1T;   K=256;  N=1024; t=blk-112; }
  else               { src=W2;   dst=W2T;   K=1024; N=256;  t=blk-176; }
  const int tpr = N >> 6;
  const int k0 = (t / tpr) << 6, n0 = (t % tpr) << 6;
  __shared__ float tile[64][65];
#pragma unroll
  for (int s=0;s<16;s++){ int f=tid+(s<<8); int r=f>>6, c=f&63;
    tile[r][c] = src[(size_t)(k0+r)*N + n0 + c]; }
  __syncthreads();
#pragma unroll
  for (int s=0;s<16;s++){ int f=tid+(s<<8); int r=f>>6, c=f&63;
    dst[(size_t)(n0+r)*K + k0 + c] = f2bf(tile[c][r]); }
}

// ---------------- K1: fused front: S,T,Q,K,V (per 16-row block, per col-chunk) ----
__global__ __launch_bounds__(256) void k_front(
  const float* __restrict__ h, const float* __restrict__ g1, const float* __restrict__ b1l,
  const float* __restrict__ bs, const float* __restrict__ be, const float* __restrict__ bd,
  const float* __restrict__ bqkv,
  const unsigned short* __restrict__ WsT, const unsigned short* __restrict__ WdT,
  const unsigned short* __restrict__ WqkvT,
  float* __restrict__ S, float* __restrict__ T,
  unsigned short* __restrict__ Qb, unsigned short* __restrict__ Kb,
  unsigned short* __restrict__ VTb)
{
  __shared__ float hs[16][256];
  __shared__ __align__(16) unsigned short xa[16*264];
  __shared__ float red1[16][16], red2[16][16];
  __shared__ float rmean[16], rinv[16];
  const int tid = threadIdx.x;
  const int rb = blockIdx.x & 63;
  const int chunk = blockIdx.x >> 6;
  const int row0 = rb * 16;
  const int b = row0 >> 8;
  const int w = tid>>6, l = tid&63, lrow = l&15, quad = l>>4;

#pragma unroll
  for (int s=0;s<4;s++){
    int f = tid + s*256; int r = f>>6, c4 = f&63;
    float4 v = ((const float4*)(h + (size_t)row0*256))[f];
    *(float4*)(&hs[r][c4*4]) = v;
  }
  __syncthreads();
  {
    int row = tid>>4, l16 = tid&15;
    if (chunk >= 2){
      float sm=0.f, sq=0.f;
#pragma unroll
      for (int j=0;j<16;j++){ float v=hs[row][l16*16+j]; sm+=v; sq+=v*v; }
      red1[row][l16]=sm; red2[row][l16]=sq;
      __syncthreads();
      if (l16==0){
        float s0=0.f,q0=0.f;
#pragma unroll
        for(int k=0;k<16;k++){ s0+=red1[row][k]; q0+=red2[row][k]; }
        float m=s0*(1.f/256.f);
        rmean[row]=m; rinv[row]=rsqrtf(q0*(1.f/256.f)-m*m+EPS);
      }
      __syncthreads();
      float m=rmean[row], iv=rinv[row];
#pragma unroll
      for (int j=0;j<16;j++){ int col=l16*16+j;
        xa[row*264+col] = f2bf((hs[row][col]-m)*iv*g1[col] + b1l[col]); }
    } else {
#pragma unroll
      for (int j=0;j<16;j++){ int col=l16*16+j; xa[row*264+col] = f2bf(hs[row][col]); }
    }
  }
  __syncthreads();
  const unsigned short* Wt;
  if (chunk==0) Wt = WsT; else if (chunk==1) Wt = WdT;
  else Wt = WqkvT + (size_t)(chunk-2)*256*256;
  floatx4 a4[4];
#pragma unroll
  for (int t=0;t<4;t++) a4[t] = (floatx4){0.f,0.f,0.f,0.f};
  for (int c=0;c<8;c++){
    shortx8 af = *(const shortx8*)(xa + lrow*264 + c*32 + quad*8);
#pragma unroll
    for (int t=0;t<4;t++){
      int n = (w*4+t)*16 + lrow;
      shortx8 bf = *(const shortx8*)(Wt + (size_t)n*256 + c*32 + quad*8);
      a4[t] = __builtin_amdgcn_mfma_f32_16x16x32_bf16(af, bf, a4[t], 0, 0, 0);
    }
  }
#pragma unroll
  for (int t=0;t<4;t++){
    int ct = w*4+t;
#pragma unroll
    for (int reg=0;reg<4;reg++){
      int row = quad*4+reg, col = ct*16+lrow;
      float v = a4[t][reg];
      if (chunk==0) S[(size_t)(row0+row)*256+col] = v + bs[col] + be[col];
      else if (chunk==1) T[(size_t)(row0+row)*256+col] = v + bd[col];
      else if (chunk==2){ float q = v + bqkv[col]; int hh=col>>5, d=col&31;
        Qb[((size_t)(b*8+hh)*256 + (row0&255)+row)*32 + d] = f2bf(q); }
      else if (chunk==3){ float q = v + bqkv[256+col]; int hh=col>>5, d=col&31;
        Kb[((size_t)(b*8+hh)*256 + (row0&255)+row)*32 + d] = f2bf(q); }
      else { float q = v + bqkv[512+col]; int hh=col>>5, d=col&31;
        VTb[((size_t)(b*8+hh)*32 + d)*256 + (row0&255)+row] = f2bf(q); }
    }
  }
}

// ---------------- K2: e_new + fused bias, register-prefetch pipeline ----------------
__global__ __launch_bounds__(256) void k_edge(
    const float* __restrict__ e, const unsigned short* __restrict__ WeT,
    const float* __restrict__ S, const float* __restrict__ T,
    const unsigned short* __restrict__ WbTg,
    float* __restrict__ eo, float* __restrict__ bias)
{
  __shared__ __align__(16) unsigned short smem[16896]; // As(64x40)+Bs(256x40) | En(64x264)
  __shared__ float sbuf[256];
  __shared__ __align__(16) unsigned short WbT[4096];
  unsigned short* As = smem;
  unsigned short* Bs = smem + 2560;
  unsigned short* En = smem;

  const int tid = threadIdx.x;
  const int blk = blockIdx.x;
  const int jt = blk & 3;
  const int i  = (blk >> 2) & 255;
  const int b  = blk >> 10;
  const int j0 = jt * 64;
  const int w = tid >> 6, l = tid & 63;
  const int lrow = l & 15, quad = l >> 4;

  sbuf[tid] = S[((b << 8) + i) * 256 + tid];
  ((uint4*)WbT)[tid]       = ((const uint4*)WbTg)[tid];
  ((uint4*)WbT)[tid + 256] = ((const uint4*)WbTg)[tid + 256];

  floatx4 acc[16];
#pragma unroll
  for (int t = 0; t < 16; t++) acc[t] = (floatx4){0.f,0.f,0.f,0.f};

  const float* eBase = e + ((size_t)((b*256 + i)*256 + j0)) * 256;
  const int rA = tid >> 3, qA = tid & 7;
  const int nB0 = tid >> 2, segB = tid & 2 ? 0 : 0; (void)segB;

  // prologue: load + stage chunk 0
  float4 pa0 = *(const float4*)(eBase + rA*256 + qA*4);
  float4 pa1 = *(const float4*)(eBase + (rA+32)*256 + qA*4);
  uint4 pb[4];
#pragma unroll
  for (int s=0;s<4;s++){ int f = tid + s*256; int n = f>>2, seg = f&3;
    pb[s] = *(const uint4*)(WeT + n*256 + seg*8); }
  {
    unsigned short* d0 = As + rA*40 + qA*4;
    d0[0]=f2bf(pa0.x); d0[1]=f2bf(pa0.y); d0[2]=f2bf(pa0.z); d0[3]=f2bf(pa0.w);
    unsigned short* d1 = As + (rA+32)*40 + qA*4;
    d1[0]=f2bf(pa1.x); d1[1]=f2bf(pa1.y); d1[2]=f2bf(pa1.z); d1[3]=f2bf(pa1.w);
#pragma unroll
    for (int s=0;s<4;s++){ int f = tid + s*256; int n = f>>2, seg = f&3;
      *(uint4*)(Bs + n*40 + seg*8) = pb[s]; }
  }
  __syncthreads();

  for (int c = 0; c < 8; c++){
    if (c < 7){
      const int k0n = (c+1)*32;
      pa0 = *(const float4*)(eBase + rA*256 + k0n + qA*4);
      pa1 = *(const float4*)(eBase + (rA+32)*256 + k0n + qA*4);
#pragma unroll
      for (int s=0;s<4;s++){ int f = tid + s*256; int n = f>>2, seg = f&3;
        pb[s] = *(const uint4*)(WeT + n*256 + k0n + seg*8); }
    }
    shortx8 af = *(const shortx8*)(As + (w*16 + lrow)*40 + quad*8);
#pragma unroll
    for (int t = 0; t < 16; t++){
      shortx8 bfr = *(const shortx8*)(Bs + (t*16 + lrow)*40 + quad*8);
      acc[t] = __builtin_amdgcn_mfma_f32_16x16x32_bf16(af, bfr, acc[t], 0, 0, 0);
    }
    __syncthreads();
    if (c < 7){
      unsigned short* d0 = As + rA*40 + qA*4;
      d0[0]=f2bf(pa0.x); d0[1]=f2bf(pa0.y); d0[2]=f2bf(pa0.z); d0[3]=f2bf(pa0.w);
      unsigned short* d1 = As + (rA+32)*40 + qA*4;
      d1[0]=f2bf(pa1.x); d1[1]=f2bf(pa1.y); d1[2]=f2bf(pa1.z); d1[3]=f2bf(pa1.w);
#pragma unroll
      for (int s=0;s<4;s++){ int f = tid + s*256; int n = f>>2, seg = f&3;
        *(uint4*)(Bs + n*40 + seg*8) = pb[s]; }
    }
    __syncthreads();
  }
  // epilogue: + S[b,i,d] + T[b,j,d], relu -> En (bf16)
  const float* Tb = T + (size_t)(b*256 + j0) * 256;
#pragma unroll
  for (int reg = 0; reg < 4; reg++){
    int rloc = w*16 + quad*4 + reg;
    const float* Trow = Tb + rloc*256;
#pragma unroll
    for (int t = 0; t < 16; t++){
      int col = t*16 + lrow;
      float v = acc[t][reg] + sbuf[col] + Trow[col];
      v = fmaxf(v, 0.f);
      En[rloc*264 + col] = f2bf(v);
    }
  }
  __syncthreads();
  // coalesced fp32 store of e_new
  float* eop = eo + ((size_t)((b*256 + i)*256 + j0)) * 256;
#pragma unroll
  for (int s = 0; s < 16; s++){
    int fi = tid + s*256;
    int r = fi >> 6, c4 = fi & 63;
    const unsigned short* src = En + r*264 + c4*4;
    float4 v = { bf2f(src[0]), bf2f(src[1]), bf2f(src[2]), bf2f(src[3]) };
    *(float4*)(eop + r*256 + c4*4) = v;
  }
  // fused bias: (64 j x 256 d) @ WbT -> [h][j]
  floatx4 accb = (floatx4){0.f,0.f,0.f,0.f};
#pragma unroll
  for (int c = 0; c < 8; c++){
    int k0 = c*32;
    shortx8 af = *(const shortx8*)(En + (w*16 + lrow)*264 + k0 + quad*8);
    shortx8 bfrag = *(const shortx8*)(WbT + lrow*256 + k0 + quad*8);
    accb = __builtin_amdgcn_mfma_f32_16x16x32_bf16(af, bfrag, accb, 0, 0, 0);
  }
  if (lrow < 8){
    float* bp = bias + ((size_t)((b*8 + lrow)*256 + i)) * 256;
    int jb = j0 + w*16 + quad*4;
#pragma unroll
    for (int r = 0; r < 4; r++) bp[jb + r] = accb[r];
  }
}

// ---------------- K2b: add bb to bias is folded here via separate tiny kernel? No:
// bb folded into k_attn's bias read instead (bias stores raw einsum; attn adds bb).

// ---------------- K3: attention, one block per (bh, 32-row i-chunk) ----------------
__global__ __launch_bounds__(256) void k_attn(
  const unsigned short* __restrict__ Qb, const unsigned short* __restrict__ Kb,
  const unsigned short* __restrict__ VTb, const float* __restrict__ bias,
  const float* __restrict__ bbv, unsigned short* __restrict__ Ob)
{
  __shared__ __align__(16) unsigned short Qa[32*40];
  __shared__ __align__(16) unsigned short Kl[256*40];
  __shared__ __align__(16) unsigned short Vt[32*264];
  __shared__ __align__(16) unsigned short Pl[32*264];
  __shared__ float srowm[4][16], srows[4][16], sinv[32];

  const int tid = threadIdx.x;
  const int ic = blockIdx.x & 7, bh = blockIdx.x >> 3;
  const int i0 = ic * 32;
  const int w = tid>>6, l = tid&63, lrow = l&15, quad = l>>4;

  if (tid < 128){
    int r = tid>>2, cseg = tid&3;
    *(uint4*)(Qa + r*40 + cseg*8) = ((const uint4*)(Qb + (size_t)(bh*256+i0)*32))[tid];
  }
#pragma unroll
  for (int s=0;s<4;s++){
    int f = tid + s*256; int r = f>>2, cseg = f&3;
    *(uint4*)(Kl + r*40 + cseg*8) = ((const uint4*)(Kb + (size_t)bh*8192))[f];
  }
#pragma unroll
  for (int s=0;s<4;s++){
    int f = tid + s*256; int r = f>>5, c8 = f&31;
    *(uint4*)(Vt + r*264 + c8*8) = ((const uint4*)(VTb + (size_t)bh*8192))[f];
  }
  __syncthreads();

  const int rt = w & 1, cs = (w>>1)*8;
  const float bbh = bbv[bh & 7];
  floatx4 sc[8];
  {
    shortx8 aq = *(const shortx8*)(Qa + (rt*16+lrow)*40 + quad*8);
    floatx4 z = (floatx4){0.f,0.f,0.f,0.f};
#pragma unroll
    for (int t=0;t<8;t++){
      shortx8 bk = *(const shortx8*)(Kl + ((cs+t)*16+lrow)*40 + quad*8);
      sc[t] = __builtin_amdgcn_mfma_f32_16x16x32_bf16(aq, bk, z, 0, 0, 0);
    }
  }
  const float scale = 0.17677669529663687f;
  float mx[4] = {-1e30f,-1e30f,-1e30f,-1e30f};
#pragma unroll
  for (int t=0;t<8;t++){
#pragma unroll
    for (int reg=0;reg<4;reg++){
      size_t bidx = ((size_t)(bh*256 + i0 + rt*16 + quad*4 + reg))*256 + (cs+t)*16 + lrow;
      float v = sc[t][reg]*scale + bias[bidx] + bbh;
      sc[t][reg] = v;
      mx[reg] = fmaxf(mx[reg], v);
    }
  }
#pragma unroll
  for (int m=1;m<16;m<<=1){
#pragma unroll
    for (int reg=0;reg<4;reg++) mx[reg] = fmaxf(mx[reg], __shfl_xor(mx[reg], m));
  }
  if (lrow == 0){
#pragma unroll
    for (int reg=0;reg<4;reg++) srowm[w][quad*4+reg] = mx[reg];
  }
  __syncthreads();
  float sum[4] = {0.f,0.f,0.f,0.f};
#pragma unroll
  for (int reg=0;reg<4;reg++){
    float gm = fmaxf(srowm[w][quad*4+reg], srowm[w^2][quad*4+reg]);
#pragma unroll
    for (int t=0;t<8;t++){
      float p = __expf(sc[t][reg] - gm);
      sc[t][reg] = p; sum[reg] += p;
    }
  }
#pragma unroll
  for (int m=1;m<16;m<<=1){
#pragma unroll
    for (int reg=0;reg<4;reg++) sum[reg] += __shfl_xor(sum[reg], m);
  }
  if (lrow == 0){
#pragma unroll
    for (int reg=0;reg<4;reg++) srows[w][quad*4+reg] = sum[reg];
  }
#pragma unroll
  for (int t=0;t<8;t++){
#pragma unroll
    for (int reg=0;reg<4;reg++)
      Pl[(rt*16+quad*4+reg)*264 + (cs+t)*16 + lrow] = f2bf(sc[t][reg]);
  }
  __syncthreads();
  if (lrow == 0 && w < 2){
#pragma unroll
    for (int reg=0;reg<4;reg++){
      int row = rt*16 + quad*4 + reg;
      sinv[row] = 1.f/(srows[w][quad*4+reg] + srows[w^2][quad*4+reg]);
    }
  }
  __syncthreads();
  // phase 2: P @ V^T
  const int rt2 = w & 1, ctd = w >> 1;
  floatx4 oc = (floatx4){0.f,0.f,0.f,0.f};
#pragma unroll
  for (int kc=0;kc<8;kc++){
    shortx8 ap = *(const shortx8*)(Pl + (rt2*16+lrow)*264 + kc*32 + quad*8);
    shortx8 bv = *(const shortx8*)(Vt + (ctd*16+lrow)*264 + kc*32 + quad*8);
    oc = __builtin_amdgcn_mfma_f32_16x16x32_bf16(ap, bv, oc, 0, 0, 0);
  }
  const int bq = bh >> 3, hh = bh & 7;
#pragma unroll
  for (int reg=0;reg<4;reg++){
    int row = rt2*16 + quad*4 + reg;
    int d = ctd*16 + lrow;
    Ob[((size_t)(bq*256 + i0 + row))*256 + hh*32 + d] = f2bf(oc[reg]*sinv[row]);
  }
}

// ---------------- K4: fused back: oproj+res+LN2+FFN1+GELU+FFN2+res ----------------
__global__ __launch_bounds__(256) void k_back(
  const unsigned short* __restrict__ Ob, const unsigned short* __restrict__ WoT,
  const float* __restrict__ bo, const float* __restrict__ h,
  const float* __restrict__ g2, const float* __restrict__ b2l,
  const unsigned short* __restrict__ W1T, const float* __restrict__ b1f,
  const unsigned short* __restrict__ W2T, const float* __restrict__ b2f,
  float* __restrict__ out)
{
  __shared__ __align__(16) unsigned short Os[16*264];
  __shared__ float h1s[16*264];
  __shared__ __align__(16) unsigned short ys[16*264];
  __shared__ __align__(16) unsigned short Gs[16*1032];
  __shared__ float red1[16][16], red2[16][16];
  __shared__ float rmean[16], rinv[16];

  const int tid = threadIdx.x;
  const int row0 = blockIdx.x * 16;
  const int w = tid>>6, l = tid&63, lrow = l&15, quad = l>>4;

#pragma unroll
  for (int s=0;s<2;s++){
    int f = tid + s*256; int r = f>>5, c8 = f&31;
    *(uint4*)(Os + r*264 + c8*8) = ((const uint4*)(Ob + (size_t)row0*256))[f];
  }
  __syncthreads();
  // GEMM1: o @ WoT + bo + h -> h1s
  {
    floatx4 a4[4];
#pragma unroll
    for (int t=0;t<4;t++) a4[t] = (floatx4){0.f,0.f,0.f,0.f};
    for (int c=0;c<8;c++){
      shortx8 af = *(const shortx8*)(Os + lrow*264 + c*32 + quad*8);
#pragma unroll
      for (int t=0;t<4;t++){
        int n = (w*4+t)*16 + lrow;
        shortx8 bf = *(const shortx8*)(WoT + (size_t)n*256 + c*32 + quad*8);
        a4[t] = __builtin_amdgcn_mfma_f32_16x16x32_bf16(af, bf, a4[t], 0, 0, 0);
      }
    }
#pragma unroll
    for (int t=0;t<4;t++){
#pragma unroll
      for (int reg=0;reg<4;reg++){
        int row = quad*4+reg, col = (w*4+t)*16+lrow;
        h1s[row*264+col] = a4[t][reg] + bo[col] + h[(size_t)(row0+row)*256 + col];
      }
    }
  }
  __syncthreads();
  // LN2 -> ys (bf16)
  {
    int row = tid>>4, l16 = tid&15;
    float sm=0.f, sq=0.f;
#pragma unroll
    for (int j=0;j<16;j++){ float v = h1s[row*264 + l16*16 + j]; sm+=v; sq+=v*v; }
    red1[row][l16]=sm; red2[row][l16]=sq;
    __syncthreads();
    if (l16==0){
      float s0=0.f,q0=0.f;
#pragma unroll
      for (int k=0;k<16;k++){ s0+=red1[row][k]; q0+=red2[row][k]; }
      float m = s0*(1.f/256.f);
      rmean[row]=m; rinv[row]=rsqrtf(q0*(1.f/256.f)-m*m+EPS);
    }
    __syncthreads();
    float m = rmean[row], iv = rinv[row];
#pragma unroll
    for (int j=0;j<16;j++){ int col = l16*16+j;
      ys[row*264+col] = f2bf((h1s[row*264+col]-m)*iv*g2[col] + b2l[col]); }
  }
  __syncthreads();
  // GEMM2: y @ W1T + b1 -> GELU -> Gs
  {
    floatx4 a4[16];
#pragma unroll
    for (int t=0;t<16;t++) a4[t] = (floatx4){0.f,0.f,0.f,0.f};
    for (int c=0;c<8;c++){
      shortx8 af = *(const shortx8*)(ys + lrow*264 + c*32 + quad*8);
#pragma unroll
      for (int t=0;t<16;t++){
        int n = (w*16+t)*16 + lrow;
        shortx8 bf = *(const shortx8*)(W1T + (size_t)n*256 + c*32 + quad*8);
        a4[t] = __builtin_amdgcn_mfma_f32_16x16x32_bf16(af, bf, a4[t], 0, 0, 0);
      }
    }
#pragma unroll
    for (int t=0;t<16;t++){
#pragma unroll
      for (int reg=0;reg<4;reg++){
        int row = quad*4+reg, col = (w*16+t)*16+lrow;
        float v = a4[t][reg] + b1f[col];
        float ge = 0.5f*v*(1.f + erff(v*0.70710678118654752f));
        Gs[row*1032+col] = f2bf(ge);
      }
    }
  }
  __syncthreads();
  // GEMM3: G @ W2T + b2 + h1 -> out
  {
    floatx4 a4[4];
#pragma unroll
    for (int t=0;t<4;t++) a4[t] = (floatx4){0.f,0.f,0.f,0.f};
    for (int c=0;c<32;c++){
      shortx8 af = *(const shortx8*)(Gs + lrow*1032 + c*32 + quad*8);
#pragma unroll
      for (int t=0;t<4;t++){
        int n = (w*4+t)*16 + lrow;
        shortx8 bf = *(const shortx8*)(W2T + (size_t)n*1024 + c*32 + quad*8);
        a4[t] = __builtin_amdgcn_mfma_f32_16x16x32_bf16(af, bf, a4[t], 0, 0, 0);
      }
    }
#pragma unroll
    for (int t=0;t<4;t++){
#pragma unroll
      for (int reg=0;reg<4;reg++){
        int row = quad*4+reg, col = (w*4+t)*16+lrow;
        out[(size_t)(row0+row)*256+col] = h1s[row*264+col] + a4[t][reg] + b2f[col];
      }
    }
  }
}

extern "C" void kernel_launch(void* const* d_in, const int* in_sizes, int n_in,
                              void* d_out, int out_size, void* d_ws, size_t ws_size,
                              hipStream_t stream)
{
  (void)in_sizes; (void)n_in; (void)out_size; (void)ws_size;
  const float* h    = (const float*)d_in[0];
  const float* e    = (const float*)d_in[1];
  const float* We   = (const float*)d_in[2];
  const float* be   = (const float*)d_in[3];
  const float* Ws   = (const float*)d_in[4];
  const float* bs   = (const float*)d_in[5];
  const float* Wd   = (const float*)d_in[6];
  const float* bd   = (const float*)d_in[7];
  const float* Wb   = (const float*)d_in[8];
  const float* bb   = (const float*)d_in[9];
  const float* g1   = (const float*)d_in[10];
  const float* b1l  = (const float*)d_in[11];
  const float* Wqkv = (const float*)d_in[12];
  const float* bqkv = (const float*)d_in[13];
  const float* Wo   = (const float*)d_in[14];
  const float* bo   = (const float*)d_in[15];
  const float* g2   = (const float*)d_in[16];
  const float* b2l  = (const float*)d_in[17];
  const float* W1   = (const float*)d_in[18];
  const float* b1f  = (const float*)d_in[19];
  const float* W2   = (const float*)d_in[20];
  const float* b2f  = (const float*)d_in[21];

  float* out  = (float*)d_out;
  float* h2_o = out;               // [B,N,D]
  float* e_o  = out + 262144;      // [B,N,N,D]

  float* wsf = (float*)d_ws;
  unsigned short* ush = (unsigned short*)d_ws;
  unsigned short* WeT   = ush;                 // 65536
  unsigned short* WsT   = ush + 65536;         // 65536
  unsigned short* WdT   = ush + 131072;        // 65536
  unsigned short* WqkvT = ush + 196608;        // 196608
  unsigned short* WoT   = ush + 393216;        // 65536
  unsigned short* W1T   = ush + 458752;        // 262144
  unsigned short* W2T   = ush + 720896;        // 262144
  unsigned short* WbT16 = ush + 983040;        // 4096  -> total 987136 ush = 493568 f
  float* S_   = wsf + 493568;                  // 262144
  float* T_   = wsf + 755712;                  // 262144
  float* bias = wsf + 1017856;                 // 2097152 -> 3115008
  unsigned short* Qb  = (unsigned short*)(wsf + 3115008); // 262144 ush
  unsigned short* Kb  = (unsigned short*)(wsf + 3246080);
  unsigned short* VTb = (unsigned short*)(wsf + 3377152);
  unsigned short* Ob  = (unsigned short*)(wsf + 3508224); // end 3639296 f (~14.6 MB)

  k_prep <<<dim3(241),  dim3(256), 0, stream>>>(We,Ws,Wd,Wqkv,Wo,W1,W2,Wb,
                                                WeT,WsT,WdT,WqkvT,WoT,W1T,W2T,WbT16);
  k_front<<<dim3(320),  dim3(256), 0, stream>>>(h, g1,b1l, bs,be,bd, bqkv,
                                                WsT,WdT,WqkvT, S_,T_, Qb,Kb,VTb);
  k_edge <<<dim3(4096), dim3(256), 0, stream>>>(e, WeT, S_, T_, WbT16, e_o, bias);
  k_attn <<<dim3(256),  dim3(256), 0, stream>>>(Qb, Kb, VTb, bias, bb, Ob);
  k_back <<<dim3(64),   dim3(256), 0, stream>>>(Ob, WoT, bo, h, g2,b2l,
                                                W1T,b1f, W2T,b2f, h2_o);
}